// Round 1
// baseline (1789.500 us; speedup 1.0000x reference)
//
#include <hip/hip_runtime.h>
#include <stdint.h>

#define HW    50176   // 224*224
#define BATCH 16
#define NSEG  196
#define EMB   16
#define MC    16
#define JITTER 0.001f

// ---------------- threefry2x32 (20 rounds), bit-exact vs JAX ----------------
__host__ __device__ inline void threefry2x32(uint32_t k0, uint32_t k1,
                                             uint32_t x0, uint32_t x1,
                                             uint32_t& o0, uint32_t& o1) {
  uint32_t k2 = k0 ^ k1 ^ 0x1BD11BDAu;
#define TFR(r) { x0 += x1; x1 = (x1 << (r)) | (x1 >> (32 - (r))); x1 ^= x0; }
  x0 += k0; x1 += k1;
  TFR(13) TFR(15) TFR(26) TFR(6)
  x0 += k1; x1 += k2 + 1u;
  TFR(17) TFR(29) TFR(16) TFR(24)
  x0 += k2; x1 += k0 + 2u;
  TFR(13) TFR(15) TFR(26) TFR(6)
  x0 += k0; x1 += k1 + 3u;
  TFR(17) TFR(29) TFR(16) TFR(24)
  x0 += k1; x1 += k2 + 4u;
  TFR(13) TFR(15) TFR(26) TFR(6)
  x0 += k2; x1 += k0 + 5u;
#undef TFR
  o0 = x0; o1 = x1;
}

// XLA ErfInv (f32), Giles polynomial — matches jax.lax.erf_inv on CPU/GPU
__device__ inline float erfinv_f32(float x) {
  float w = -log1pf(-x * x);
  float p;
  if (w < 5.0f) {
    w = w - 2.5f;
    p = 2.81022636e-08f;
    p = 3.43273939e-07f + p * w;
    p = -3.5233877e-06f + p * w;
    p = -4.39150654e-06f + p * w;
    p = 0.00021858087f + p * w;
    p = -0.00125372503f + p * w;
    p = -0.00417768164f + p * w;
    p = 0.246640727f + p * w;
    p = 1.50140941f + p * w;
  } else {
    w = sqrtf(w) - 3.0f;
    p = -0.000200214257f;
    p = 0.000100950558f + p * w;
    p = 0.00134934322f + p * w;
    p = -0.00367342844f + p * w;
    p = 0.00573950773f + p * w;
    p = -0.0076224613f + p * w;
    p = 0.00943887047f + p * w;
    p = 1.00167406f + p * w;
    p = 2.83297682f + p * w;
  }
  return p * x;
}

__device__ inline float bits_to_f01(uint32_t bits) {
  uint32_t fb = (bits >> 9) | 0x3F800000u;
  return __uint_as_float(fb) - 1.0f;
}

// ---------------- K1: emb + pixel_probs + LDS-staged segment sums ----------
__global__ __launch_bounds__(256) void emb_kernel(
    const float* __restrict__ x, const int* __restrict__ groups,
    const float* __restrict__ Wc, const float* __restrict__ bc,
    float* __restrict__ sums /* BATCH*NSEG*17, pre-zeroed */,
    float* __restrict__ pixel_probs) {
  __shared__ float lsum[NSEG * 17];
  int b = blockIdx.x / 49;
  int blk = blockIdx.x % 49;
  int tid = threadIdx.x;
  for (int i = tid; i < NSEG * 17; i += 256) lsum[i] = 0.0f;
  __syncthreads();
  const float* xb = x + (size_t)b * 3 * HW;
  for (int k = 0; k < 4; ++k) {
    int p = blk * 1024 + k * 256 + tid;
    float x0 = xb[p], x1 = xb[HW + p], x2 = xb[2 * HW + p];
    int g = groups[b * HW + p];
    float* dst = lsum + g * 17;
#pragma unroll
    for (int j = 0; j < EMB; ++j) {
      float e = Wc[j * 3 + 0] * x0 + Wc[j * 3 + 1] * x1;
      e = e + Wc[j * 3 + 2] * x2 + bc[j];
      if (j == 0) pixel_probs[b * HW + p] = 1.0f / (1.0f + expf(-e));
      atomicAdd(&dst[j], e);
    }
    atomicAdd(&dst[16], 1.0f);
  }
  __syncthreads();
  float* gs = sums + b * NSEG * 17;
  for (int i = tid; i < NSEG * 17; i += 256) atomicAdd(&gs[i], lsum[i]);
}

// ---------------- K2: avg -> mu, group_probs, sigma (=G G^T + jitter) ------
__global__ __launch_bounds__(256) void sigma_kernel(
    const float* __restrict__ sums, float* __restrict__ mu_ws,
    float* __restrict__ group_probs, float* __restrict__ sigma_out,
    float* __restrict__ Lbuf) {
  int b = blockIdx.x;
  int tid = threadIdx.x;
  __shared__ float ge[NSEG][15];
  if (tid < NSEG) {
    const float* sp = sums + (b * NSEG + tid) * 17;
    float denom = fmaxf(sp[16], 1.0f);
    float m = sp[0] / denom;
    mu_ws[b * NSEG + tid] = m;
    group_probs[b * NSEG + tid] = 1.0f / (1.0f + expf(-m));
#pragma unroll
    for (int j = 0; j < 15; ++j) ge[tid][j] = sp[j + 1] / denom;
  }
  __syncthreads();
  for (int idx = tid; idx < NSEG * NSEG; idx += 256) {
    int s = idx / NSEG, t = idx % NSEG;
    float acc = 0.0f;
#pragma unroll
    for (int j = 0; j < 15; ++j) acc = fmaf(ge[s][j], ge[t][j], acc);
    if (s == t) acc += JITTER;
    size_t o = (size_t)(b * NSEG + s) * NSEG + t;
    sigma_out[o] = acc;
    Lbuf[o] = acc;
  }
}

// ---------------- K3: per-batch right-looking Cholesky (lower) -------------
__global__ __launch_bounds__(256) void chol_kernel(float* __restrict__ A_) {
  int b = blockIdx.x;
  float* A = A_ + (size_t)b * NSEG * NSEG;
  int tid = threadIdx.x;
  __shared__ float col[NSEG];
  __shared__ float sdiag;
  for (int k = 0; k < NSEG; ++k) {
    if (tid == 0) {
      float d = sqrtf(A[k * NSEG + k]);
      A[k * NSEG + k] = d;
      sdiag = d;
    }
    __syncthreads();
    float inv = 1.0f / sdiag;
    for (int i = k + 1 + tid; i < NSEG; i += 256) {
      float v = A[i * NSEG + k] * inv;
      A[i * NSEG + k] = v;
      col[i] = v;
    }
    __syncthreads();
    int n = NSEG - 1 - k;
    int total = n * (n + 1) / 2;
    for (int idx = tid; idx < total; idx += 256) {
      int r = (int)((sqrtf(8.0f * (float)idx + 1.0f) - 1.0f) * 0.5f);
      while ((r + 1) * (r + 2) / 2 <= idx) ++r;
      while (r * (r + 1) / 2 > idx) --r;
      int c = idx - r * (r + 1) / 2;
      int i = k + 1 + r, j = k + 1 + c;
      A[i * NSEG + j] = fmaf(-col[i], col[j], A[i * NSEG + j]);
    }
    __syncthreads();
  }
}

// ---------------- K4a: threefry -> eps (normal) and logistic noise ---------
__global__ __launch_bounds__(256) void rng_kernel(
    uint32_t kg0, uint32_t kg1, uint32_t ku0, uint32_t ku1,
    float* __restrict__ eps, float* __restrict__ logist) {
  int j = blockIdx.x * blockDim.x + threadIdx.x;
  if (j >= BATCH * NSEG * MC) return;
  uint32_t a0, a1;
  // partitionable mode: bits[j] = o0 ^ o1 of threefry(key, (hi(j)=0, lo(j)=j))
  threefry2x32(kg0, kg1, 0u, (uint32_t)j, a0, a1);
  float f = bits_to_f01(a0 ^ a1);
  const float lo = -0.99999994f;           // nextafter(-1,0) in f32
  float u = fmaxf(lo, f * (1.0f - lo) + lo);  // (1-lo) folds to 2.0f like XLA
  eps[j] = 1.4142135623730951f * erfinv_f32(u);

  threefry2x32(ku0, ku1, 0u, (uint32_t)j, a0, a1);
  f = bits_to_f01(a0 ^ a1);
  const float mn = 1e-6f;
  const float mx = (float)(1.0 - 1e-6);    // python-double sub, then f32 cast
  float uu = fmaxf(mn, f * (mx - mn) + mn);
  logist[j] = logf(uu) - log1pf(-uu);
}

// ---------------- K4b: logits = mu + L@eps; hard bits ----------------------
__global__ __launch_bounds__(256) void logits_kernel(
    const float* __restrict__ L, const float* __restrict__ mu,
    const float* __restrict__ eps, const float* __restrict__ logist,
    float* __restrict__ hard) {
  int id = blockIdx.x * blockDim.x + threadIdx.x;
  if (id >= BATCH * NSEG * MC) return;
  int m = id & (MC - 1);
  int s = (id >> 4) % NSEG;
  int b = id / (NSEG * MC);
  const float* Lrow = L + (size_t)(b * NSEG + s) * NSEG;
  const float* ec = eps + b * NSEG * MC + m;
  float acc = 0.0f;
  for (int t = 0; t <= s; ++t) acc = fmaf(Lrow[t], ec[t * MC], acc);
  float z = mu[b * NSEG + s] + acc + logist[id];
  hard[id] = (z > 0.0f) ? 1.0f : 0.0f;
}

// ---------------- K5: mask gather + broadcast over C -----------------------
__global__ __launch_bounds__(256) void mask_kernel(
    const int* __restrict__ groups, const float* __restrict__ hard,
    float4* __restrict__ out) {
  int id = blockIdx.x * blockDim.x + threadIdx.x;  // (b*3+c)*HW + p
  if (id >= BATCH * 3 * HW) return;
  int p = id % HW;
  int b = id / (3 * HW);
  int g = groups[b * HW + p];
  const float4* src = (const float4*)(hard + (size_t)(b * NSEG + g) * MC);
  float4 v0 = src[0], v1 = src[1], v2 = src[2], v3 = src[3];
  float4* dst = out + (size_t)id * 4;
  dst[0] = v0; dst[1] = v1; dst[2] = v2; dst[3] = v3;
}

extern "C" void kernel_launch(void* const* d_in, const int* in_sizes, int n_in,
                              void* d_out, int out_size, void* d_ws, size_t ws_size,
                              hipStream_t stream) {
  const float* x = (const float*)d_in[0];
  const int* groups = (const int*)d_in[1];
  const float* Wc = (const float*)d_in[2];
  const float* bc = (const float*)d_in[3];

  float* out = (float*)d_out;
  float* mask_out = out;                         // 38,535,168
  float* gp_out = out + 38535168;                //      3,136
  float* pp_out = gp_out + 3136;                 //    802,816
  float* sig_out = pp_out + 802816;              //    614,656

  float* ws = (float*)d_ws;
  float* sums   = ws;                            //  53,312 (zeroed)
  float* mu_ws  = ws + 53312;                    //   3,136
  float* Lbuf   = ws + 56448;                    // 614,656
  float* eps    = ws + 671104;                   //  50,176
  float* logist = ws + 721280;                   //  50,176
  float* hard   = ws + 771456;                   //  50,176  (tot 3.29 MB)

  hipMemsetAsync(sums, 0, (size_t)53312 * sizeof(float), stream);

  emb_kernel<<<BATCH * 49, 256, 0, stream>>>(x, groups, Wc, bc, sums, pp_out);
  sigma_kernel<<<BATCH, 256, 0, stream>>>(sums, mu_ws, gp_out, sig_out, Lbuf);
  chol_kernel<<<BATCH, 256, 0, stream>>>(Lbuf);

  // fold-like split of key(42): kg = tf(key,(0,0)), ku = tf(key,(0,1))
  uint32_t kg0, kg1, ku0, ku1;
  threefry2x32(0u, 42u, 0u, 0u, kg0, kg1);
  threefry2x32(0u, 42u, 0u, 1u, ku0, ku1);

  int nrand = BATCH * NSEG * MC;  // 50,176
  rng_kernel<<<(nrand + 255) / 256, 256, 0, stream>>>(kg0, kg1, ku0, ku1, eps, logist);
  logits_kernel<<<(nrand + 255) / 256, 256, 0, stream>>>(Lbuf, mu_ws, eps, logist, hard);
  mask_kernel<<<(BATCH * 3 * HW + 255) / 256, 256, 0, stream>>>(groups, hard, (float4*)mask_out);
}

// Round 2
// 444.190 us; speedup vs baseline: 4.0287x; 4.0287x over previous
//
#include <hip/hip_runtime.h>
#include <stdint.h>

#define HW    50176   // 224*224
#define BATCH 16
#define NSEG  196
#define EMB   16
#define MC    16
#define JITTER 0.001f

// ---------------- threefry2x32 (20 rounds), bit-exact vs JAX ----------------
__host__ __device__ inline void threefry2x32(uint32_t k0, uint32_t k1,
                                             uint32_t x0, uint32_t x1,
                                             uint32_t& o0, uint32_t& o1) {
  uint32_t k2 = k0 ^ k1 ^ 0x1BD11BDAu;
#define TFR(r) { x0 += x1; x1 = (x1 << (r)) | (x1 >> (32 - (r))); x1 ^= x0; }
  x0 += k0; x1 += k1;
  TFR(13) TFR(15) TFR(26) TFR(6)
  x0 += k1; x1 += k2 + 1u;
  TFR(17) TFR(29) TFR(16) TFR(24)
  x0 += k2; x1 += k0 + 2u;
  TFR(13) TFR(15) TFR(26) TFR(6)
  x0 += k0; x1 += k1 + 3u;
  TFR(17) TFR(29) TFR(16) TFR(24)
  x0 += k1; x1 += k2 + 4u;
  TFR(13) TFR(15) TFR(26) TFR(6)
  x0 += k2; x1 += k0 + 5u;
#undef TFR
  o0 = x0; o1 = x1;
}

// XLA ErfInv (f32), Giles polynomial
__device__ inline float erfinv_f32(float x) {
  float w = -log1pf(-x * x);
  float p;
  if (w < 5.0f) {
    w = w - 2.5f;
    p = 2.81022636e-08f;
    p = 3.43273939e-07f + p * w;
    p = -3.5233877e-06f + p * w;
    p = -4.39150654e-06f + p * w;
    p = 0.00021858087f + p * w;
    p = -0.00125372503f + p * w;
    p = -0.00417768164f + p * w;
    p = 0.246640727f + p * w;
    p = 1.50140941f + p * w;
  } else {
    w = sqrtf(w) - 3.0f;
    p = -0.000200214257f;
    p = 0.000100950558f + p * w;
    p = 0.00134934322f + p * w;
    p = -0.00367342844f + p * w;
    p = 0.00573950773f + p * w;
    p = -0.0076224613f + p * w;
    p = 0.00943887047f + p * w;
    p = 1.00167406f + p * w;
    p = 2.83297682f + p * w;
  }
  return p * x;
}

__device__ inline float bits_to_f01(uint32_t bits) {
  uint32_t fb = (bits >> 9) | 0x3F800000u;
  return __uint_as_float(fb) - 1.0f;
}

// ---------------- K1: emb + pixel_probs + LDS-staged segment sums ----------
__global__ __launch_bounds__(256) void emb_kernel(
    const float* __restrict__ x, const int* __restrict__ groups,
    const float* __restrict__ Wc, const float* __restrict__ bc,
    float* __restrict__ sums /* BATCH*NSEG*17, pre-zeroed */,
    float* __restrict__ pixel_probs) {
  __shared__ float lsum[NSEG * 17];
  int b = blockIdx.x / 49;
  int blk = blockIdx.x % 49;
  int tid = threadIdx.x;
  for (int i = tid; i < NSEG * 17; i += 256) lsum[i] = 0.0f;
  __syncthreads();
  const float* xb = x + (size_t)b * 3 * HW;
  for (int k = 0; k < 4; ++k) {
    int p = blk * 1024 + k * 256 + tid;
    float x0 = xb[p], x1 = xb[HW + p], x2 = xb[2 * HW + p];
    int g = groups[b * HW + p];
    float* dst = lsum + g * 17;
#pragma unroll
    for (int j = 0; j < EMB; ++j) {
      float e = Wc[j * 3 + 0] * x0 + Wc[j * 3 + 1] * x1;
      e = e + Wc[j * 3 + 2] * x2 + bc[j];
      if (j == 0) pixel_probs[b * HW + p] = 1.0f / (1.0f + expf(-e));
      atomicAdd(&dst[j], e);
    }
    atomicAdd(&dst[16], 1.0f);
  }
  __syncthreads();
  float* gs = sums + b * NSEG * 17;
  for (int i = tid; i < NSEG * 17; i += 256) atomicAdd(&gs[i], lsum[i]);
}

// ---------------- K2: avg -> mu, group_probs, sigma, and Gbuf --------------
__global__ __launch_bounds__(256) void sigma_kernel(
    const float* __restrict__ sums, float* __restrict__ mu_ws,
    float* __restrict__ group_probs, float* __restrict__ sigma_out,
    float* __restrict__ Gbuf /* [B][NSEG][15] */) {
  int b = blockIdx.x;
  int tid = threadIdx.x;
  __shared__ float ge[NSEG][15];
  if (tid < NSEG) {
    const float* sp = sums + (b * NSEG + tid) * 17;
    float denom = fmaxf(sp[16], 1.0f);
    float m = sp[0] / denom;
    mu_ws[b * NSEG + tid] = m;
    group_probs[b * NSEG + tid] = 1.0f / (1.0f + expf(-m));
    float* gout = Gbuf + (size_t)(b * NSEG + tid) * 15;
#pragma unroll
    for (int j = 0; j < 15; ++j) {
      float v = sp[j + 1] / denom;
      ge[tid][j] = v;
      gout[j] = v;
    }
  }
  __syncthreads();
  for (int idx = tid; idx < NSEG * NSEG; idx += 256) {
    int s = idx / NSEG, t = idx % NSEG;
    float acc = 0.0f;
#pragma unroll
    for (int j = 0; j < 15; ++j) acc = fmaf(ge[s][j], ge[t][j], acc);
    if (s == t) acc += JITTER;
    sigma_out[(size_t)(b * NSEG + s) * NSEG + t] = acc;
  }
}

// ---------------- K3: threefry -> eps (normal) and logistic noise ----------
__global__ __launch_bounds__(256) void rng_kernel(
    uint32_t kg0, uint32_t kg1, uint32_t ku0, uint32_t ku1,
    float* __restrict__ eps, float* __restrict__ logist) {
  int j = blockIdx.x * blockDim.x + threadIdx.x;
  if (j >= BATCH * NSEG * MC) return;
  uint32_t a0, a1;
  threefry2x32(kg0, kg1, 0u, (uint32_t)j, a0, a1);
  float f = bits_to_f01(a0 ^ a1);
  const float lo = -0.99999994f;              // nextafter(-1,0) in f32
  float u = fmaxf(lo, f * (1.0f - lo) + lo);  // (1-lo) folds to 2.0f like XLA
  eps[j] = 1.4142135623730951f * erfinv_f32(u);

  threefry2x32(ku0, ku1, 0u, (uint32_t)j, a0, a1);
  f = bits_to_f01(a0 ^ a1);
  const float mn = 1e-6f;
  const float mx = (float)(1.0 - 1e-6);
  float uu = fmaxf(mn, f * (mx - mn) + mn);
  logist[j] = logf(uu) - log1pf(-uu);
}

// ---------------- K4: fused low-rank Cholesky + L@eps + hard bits ----------
// sigma = jitter*I + G G^T, G = [B][196][15].  Invariant: trailing Schur
// complement stays jitter*I + G'G'^T.  Per step k:
//   d = sqrt(j + |g_k|^2);  L[i,k] = g_i.g_k / d;
//   g_i -= beta*(g_i.g_k)*g_k,  beta = 1/(d*(d+sqrt(j)))
// L columns are consumed immediately as rank-1 updates into acc = L@eps.
// One wave per batch; G rows live in registers (4 rows/lane); row-k
// broadcast via __shfl. No barriers, no global traffic in the k-loop.
__global__ __launch_bounds__(64) void cholmc_kernel(
    const float* __restrict__ G, const float* __restrict__ mu,
    const float* __restrict__ eps, const float* __restrict__ logist,
    float* __restrict__ hard) {
  int b = blockIdx.x;
  int lane = threadIdx.x;
  __shared__ float eps_lds[NSEG * MC];  // 12544 floats = 50 KB
  const float* eb = eps + (size_t)b * NSEG * MC;
  for (int i = lane; i < NSEG * MC / 4; i += 64)
    ((float4*)eps_lds)[i] = ((const float4*)eb)[i];

  float g[4][15];
  float acc[4][16];
#pragma unroll
  for (int s = 0; s < 4; ++s) {
    int i = s * 64 + lane;
#pragma unroll
    for (int j = 0; j < 15; ++j)
      g[s][j] = (i < NSEG) ? G[((size_t)b * NSEG + i) * 15 + j] : 0.0f;
#pragma unroll
    for (int m = 0; m < 16; ++m) acc[s][m] = 0.0f;
  }
  __syncthreads();  // single wave: cheap; makes eps_lds visible

  const float sj = 0.031622776601683794f;  // sqrt(jitter)
  for (int k = 0; k < NSEG; ++k) {
    int owner = k & 63;
    int slot_k = k >> 6;  // wave-uniform
    float gk[15];
    switch (slot_k) {  // uniform branch; 15 bpermutes per step
      case 0:
#pragma unroll
        for (int j = 0; j < 15; ++j) gk[j] = __shfl(g[0][j], owner, 64);
        break;
      case 1:
#pragma unroll
        for (int j = 0; j < 15; ++j) gk[j] = __shfl(g[1][j], owner, 64);
        break;
      case 2:
#pragma unroll
        for (int j = 0; j < 15; ++j) gk[j] = __shfl(g[2][j], owner, 64);
        break;
      default:
#pragma unroll
        for (int j = 0; j < 15; ++j) gk[j] = __shfl(g[3][j], owner, 64);
        break;
    }
    float nrm = 0.0f;
#pragma unroll
    for (int j = 0; j < 15; ++j) nrm = fmaf(gk[j], gk[j], nrm);
    float dd = sqrtf(JITTER + nrm);
    float invd = 1.0f / dd;                 // precise IEEE divide
    float beta = 1.0f / (dd * (dd + sj));   // stable: no /|g|^2
    float ek[16];
#pragma unroll
    for (int q = 0; q < 4; ++q) {
      float4 t = ((const float4*)(eps_lds + k * 16))[q];
      ek[4 * q] = t.x; ek[4 * q + 1] = t.y; ek[4 * q + 2] = t.z; ek[4 * q + 3] = t.w;
    }
#pragma unroll
    for (int s = 0; s < 4; ++s) {
      int i = s * 64 + lane;
      float dot = 0.0f;
#pragma unroll
      for (int j = 0; j < 15; ++j) dot = fmaf(g[s][j], gk[j], dot);
      float lik = (i == k) ? dd : dot * invd;
      float w = (i >= k && i < NSEG) ? lik : 0.0f;
#pragma unroll
      for (int m = 0; m < 16; ++m) acc[s][m] = fmaf(w, ek[m], acc[s][m]);
      float bd = beta * dot;
#pragma unroll
      for (int j = 0; j < 15; ++j) g[s][j] = fmaf(-bd, gk[j], g[s][j]);
    }
  }

  // epilogue: hard = (mu + L@eps + logistic) > 0
#pragma unroll
  for (int s = 0; s < 4; ++s) {
    int i = s * 64 + lane;
    if (i < NSEG) {
      float mui = mu[b * NSEG + i];
      const float* lg = logist + ((size_t)b * NSEG + i) * 16;
      float4 outv[4];
      float* op = (float*)outv;
#pragma unroll
      for (int m = 0; m < 16; ++m) {
        float z = mui + acc[s][m] + lg[m];
        op[m] = (z > 0.0f) ? 1.0f : 0.0f;
      }
      float4* hp = (float4*)(hard + ((size_t)b * NSEG + i) * 16);
#pragma unroll
      for (int q = 0; q < 4; ++q) hp[q] = outv[q];
    }
  }
}

// ---------------- K5: mask gather + broadcast over C -----------------------
__global__ __launch_bounds__(256) void mask_kernel(
    const int* __restrict__ groups, const float* __restrict__ hard,
    float4* __restrict__ out) {
  int id = blockIdx.x * blockDim.x + threadIdx.x;  // (b*3+c)*HW + p
  if (id >= BATCH * 3 * HW) return;
  int p = id % HW;
  int b = id / (3 * HW);
  int g = groups[b * HW + p];
  const float4* src = (const float4*)(hard + (size_t)(b * NSEG + g) * MC);
  float4 v0 = src[0], v1 = src[1], v2 = src[2], v3 = src[3];
  float4* dst = out + (size_t)id * 4;
  dst[0] = v0; dst[1] = v1; dst[2] = v2; dst[3] = v3;
}

extern "C" void kernel_launch(void* const* d_in, const int* in_sizes, int n_in,
                              void* d_out, int out_size, void* d_ws, size_t ws_size,
                              hipStream_t stream) {
  const float* x = (const float*)d_in[0];
  const int* groups = (const int*)d_in[1];
  const float* Wc = (const float*)d_in[2];
  const float* bc = (const float*)d_in[3];

  float* out = (float*)d_out;
  float* mask_out = out;                         // 38,535,168
  float* gp_out = out + 38535168;                //      3,136
  float* pp_out = gp_out + 3136;                 //    802,816
  float* sig_out = pp_out + 802816;              //    614,656

  float* ws = (float*)d_ws;
  float* sums   = ws;                            //  53,312 (zeroed)
  float* mu_ws  = ws + 53312;                    //   3,136
  float* Gbuf   = ws + 56448;                    //  47,040
  float* eps    = ws + 103488;                   //  50,176
  float* logist = ws + 153664;                   //  50,176
  float* hard   = ws + 203840;                   //  50,176

  hipMemsetAsync(sums, 0, (size_t)53312 * sizeof(float), stream);

  emb_kernel<<<BATCH * 49, 256, 0, stream>>>(x, groups, Wc, bc, sums, pp_out);
  sigma_kernel<<<BATCH, 256, 0, stream>>>(sums, mu_ws, gp_out, sig_out, Gbuf);

  uint32_t kg0, kg1, ku0, ku1;
  threefry2x32(0u, 42u, 0u, 0u, kg0, kg1);
  threefry2x32(0u, 42u, 0u, 1u, ku0, ku1);

  int nrand = BATCH * NSEG * MC;  // 50,176
  rng_kernel<<<(nrand + 255) / 256, 256, 0, stream>>>(kg0, kg1, ku0, ku1, eps, logist);
  cholmc_kernel<<<BATCH, 64, 0, stream>>>(Gbuf, mu_ws, eps, logist, hard);
  mask_kernel<<<(BATCH * 3 * HW + 255) / 256, 256, 0, stream>>>(groups, hard, (float4*)mask_out);
}